// Round 1
// baseline (435.110 us; speedup 1.0000x reference)
//
#include <hip/hip_runtime.h>
#include <hip/hip_bf16.h>

typedef __attribute__((ext_vector_type(8))) short bf16x8;
typedef __attribute__((ext_vector_type(4))) float f32x4;

#define NN 4096
#define DD 64
#define LL 16

// manual bf16 RNE conversion (avoids bf16 API variance); matches __float2bfloat16 for normal data
__device__ __forceinline__ ushort f2bf(float f) {
    unsigned int u = __float_as_uint(f);
    unsigned int r = u + 0x7FFFu + ((u >> 16) & 1u);
    return (ushort)(r >> 16);
}
__device__ __forceinline__ float bf2f(ushort u) {
    return __uint_as_float(((unsigned int)u) << 16);
}

// Transpose (N,D,L) fp32 -> (L,N,D) bf16, and h[l][n] = 0.5 * sum_d bf16(x)^2
// One block per input row n; blockIdx.y selects X or Y.
__global__ void prep_kernel(const float* __restrict__ X, const float* __restrict__ Y,
                            ushort* __restrict__ Xb, ushort* __restrict__ Yb,
                            float* __restrict__ hx, float* __restrict__ hy) {
    const float* in = blockIdx.y ? Y : X;
    ushort* outb    = blockIdx.y ? Yb : Xb;
    float* h        = blockIdx.y ? hy : hx;

    __shared__ float lds[64 * 17];
    __shared__ float psum[16][17];

    int n = blockIdx.x;
    int t = threadIdx.x;            // 256 threads
    const float* row = in + (size_t)n * (DD * LL);   // 1024 contiguous fp32 (d,l) l-fastest

#pragma unroll
    for (int r = 0; r < 4; ++r) {
        int e = t + r * 256;        // e = d*16 + l
        lds[(e >> 4) * 17 + (e & 15)] = row[e];
    }
    __syncthreads();

    int l = t >> 4, c = t & 15;     // thread handles (l, d = c*4..c*4+3)
    float p = 0.f;
    ushort4 w;
    {
        float v0 = lds[(c * 4 + 0) * 17 + l];
        float v1 = lds[(c * 4 + 1) * 17 + l];
        float v2 = lds[(c * 4 + 2) * 17 + l];
        float v3 = lds[(c * 4 + 3) * 17 + l];
        ushort u0 = f2bf(v0), u1 = f2bf(v1), u2 = f2bf(v2), u3 = f2bf(v3);
        float b0 = bf2f(u0), b1 = bf2f(u1), b2 = bf2f(u2), b3 = bf2f(u3);
        p = b0 * b0 + b1 * b1 + b2 * b2 + b3 * b3;
        w.x = u0; w.y = u1; w.z = u2; w.w = u3;
    }
    *reinterpret_cast<ushort4*>(outb + ((size_t)l * NN + n) * DD + c * 4) = w;

    psum[l][c] = p;
    __syncthreads();
    if (t < 16) {
        float s = 0.f;
#pragma unroll
        for (int i = 0; i < 16; ++i) s += psum[t][i];
        h[t * NN + n] = 0.5f * s;
    }
}

// Main fused kernel: per wave, 32 i-rows x (2048 j as 64 iters of 32).
// Gram via MFMA bf16 (A = rows of X/Y, B = same layout -> A*B^T), then
// K = exp(G - h_i - h_j); accumulate T1 and row sums.
__global__ __launch_bounds__(256) void hsic_main(
    const ushort* __restrict__ Xb, const ushort* __restrict__ Yb,
    const float* __restrict__ hx, const float* __restrict__ hy,
    float* __restrict__ a_raw, float* __restrict__ b_raw, float* __restrict__ t1) {

    int blk = blockIdx.x;               // 1024 blocks
    int l = blk >> 6;
    int r = blk & 63;
    int itile = r >> 1;                 // 0..31 (128 rows each)
    int jc = r & 1;                     // j half: 0 or 1

    int wave = threadIdx.x >> 6;
    int lane = threadIdx.x & 63;
    int lrow = lane & 15;               // A/B fragment row/col
    int khi  = lane >> 4;               // k-chunk selector

    int ibase = itile * 128 + wave * 32;

    const ushort* Xl = Xb + (size_t)l * (NN * DD);
    const ushort* Yl = Yb + (size_t)l * (NN * DD);
    const float* hxl = hx + l * NN;
    const float* hyl = hy + l * NN;

    // A fragments (i rows), fixed for the whole j loop
    bf16x8 ax[2][2], ay[2][2];
    float hxi[2][4], hyi[2][4];
#pragma unroll
    for (int rg = 0; rg < 2; ++rg) {
        int arow = ibase + rg * 16 + lrow;
#pragma unroll
        for (int kc = 0; kc < 2; ++kc) {
            ax[rg][kc] = *reinterpret_cast<const bf16x8*>(Xl + (size_t)arow * DD + kc * 32 + khi * 8);
            ay[rg][kc] = *reinterpret_cast<const bf16x8*>(Yl + (size_t)arow * DD + kc * 32 + khi * 8);
        }
        int crow = ibase + rg * 16 + khi * 4;   // C-layout row base for this lane
#pragma unroll
        for (int q = 0; q < 4; ++q) {
            hxi[rg][q] = hxl[crow + q];
            hyi[rg][q] = hyl[crow + q];
        }
    }

    float rpx[2][4] = {}, rpy[2][4] = {};
    float t1acc = 0.f;

    for (int it = 0; it < 64; ++it) {
        int jbase = jc * 2048 + it * 32;

        bf16x8 bx[2][2], by[2][2];
        float hxj[2], hyj[2];
#pragma unroll
        for (int cg = 0; cg < 2; ++cg) {
            int brow = jbase + cg * 16 + lrow;
#pragma unroll
            for (int kc = 0; kc < 2; ++kc) {
                bx[cg][kc] = *reinterpret_cast<const bf16x8*>(Xl + (size_t)brow * DD + kc * 32 + khi * 8);
                by[cg][kc] = *reinterpret_cast<const bf16x8*>(Yl + (size_t)brow * DD + kc * 32 + khi * 8);
            }
            hxj[cg] = hxl[jbase + cg * 16 + lrow];
            hyj[cg] = hyl[jbase + cg * 16 + lrow];
        }

        f32x4 gx[2][2] = {};
        f32x4 gy[2][2] = {};
#pragma unroll
        for (int rg = 0; rg < 2; ++rg)
#pragma unroll
            for (int cg = 0; cg < 2; ++cg) {
#pragma unroll
                for (int kc = 0; kc < 2; ++kc) {
                    gx[rg][cg] = __builtin_amdgcn_mfma_f32_16x16x32_bf16(ax[rg][kc], bx[cg][kc], gx[rg][cg], 0, 0, 0);
                    gy[rg][cg] = __builtin_amdgcn_mfma_f32_16x16x32_bf16(ay[rg][kc], by[cg][kc], gy[rg][cg], 0, 0, 0);
                }
            }

        // epilogue: K = exp(G - h_i - h_j); C layout: col = lane&15 (j), row = khi*4+q (i)
#pragma unroll
        for (int rg = 0; rg < 2; ++rg)
#pragma unroll
            for (int cg = 0; cg < 2; ++cg)
#pragma unroll
                for (int q = 0; q < 4; ++q) {
                    float kxv = __expf(gx[rg][cg][q] - hxi[rg][q] - hxj[cg]);
                    float kyv = __expf(gy[rg][cg][q] - hyi[rg][q] - hyj[cg]);
                    rpx[rg][q] += kxv;
                    rpy[rg][q] += kyv;
                    t1acc = __builtin_fmaf(kxv, kyv, t1acc);
                }
    }

    // row-sum reduce across the 16 lanes sharing a C-row (lane bits 0..3)
#pragma unroll
    for (int rg = 0; rg < 2; ++rg)
#pragma unroll
        for (int q = 0; q < 4; ++q) {
            float vx = rpx[rg][q], vy = rpy[rg][q];
#pragma unroll
            for (int s = 1; s < 16; s <<= 1) {
                vx += __shfl_xor(vx, s);
                vy += __shfl_xor(vy, s);
            }
            if (lrow == 0) {
                int row = ibase + rg * 16 + khi * 4 + q;
                atomicAdd(&a_raw[l * NN + row], vx);
                atomicAdd(&b_raw[l * NN + row], vy);
            }
        }

    float v = t1acc;
#pragma unroll
    for (int s = 1; s < 64; s <<= 1) v += __shfl_xor(v, s);
    if (lane == 0) atomicAdd(&t1[l], v);
}

// Combine: S_l = T1 - (2/n) sum A_i B_i + (sum A)(sum B)/n^2 ; out = sum_l S_l/(n-1)^2
__global__ void finalize_kernel(const float* __restrict__ a_raw, const float* __restrict__ b_raw,
                                const float* __restrict__ t1, float* __restrict__ out) {
    __shared__ float sh[256];
    int t = threadIdx.x;
    float total = 0.f;
    for (int l = 0; l < LL; ++l) {
        float sab = 0.f, sa = 0.f, sb = 0.f;
        for (int i = t; i < NN; i += 256) {
            float av = a_raw[l * NN + i], bv = b_raw[l * NN + i];
            sab += av * bv;
            sa += av;
            sb += bv;
        }
        float vals[3] = {sab, sa, sb};
        float red[3];
        for (int k = 0; k < 3; ++k) {
            __syncthreads();
            sh[t] = vals[k];
            __syncthreads();
            for (int s = 128; s > 0; s >>= 1) {
                if (t < s) sh[t] += sh[t + s];
                __syncthreads();
            }
            red[k] = sh[0];
        }
        if (t == 0) {
            const float n = (float)NN;
            float S = t1[l] - (2.f / n) * red[0] + (red[1] * red[2]) / (n * n);
            total += S / (4095.f * 4095.f);
        }
    }
    if (t == 0) out[0] = total;
}

extern "C" void kernel_launch(void* const* d_in, const int* in_sizes, int n_in,
                              void* d_out, int out_size, void* d_ws, size_t ws_size,
                              hipStream_t stream) {
    const float* X = (const float*)d_in[0];
    const float* Y = (const float*)d_in[1];
    float* out = (float*)d_out;
    char* ws = (char*)d_ws;

    // workspace layout (bytes)
    const size_t XB_OFF  = 0;                       // L*N*D bf16 = 8388608
    const size_t YB_OFF  = 8388608;
    const size_t HX_OFF  = 16777216;                // L*N fp32 = 262144
    const size_t HY_OFF  = 17039360;
    const size_t A_OFF   = 17301504;                // L*N fp32
    const size_t B_OFF   = 17563648;
    const size_t T1_OFF  = 17825792;                // L fp32

    ushort* Xb  = (ushort*)(ws + XB_OFF);
    ushort* Yb  = (ushort*)(ws + YB_OFF);
    float* hx   = (float*)(ws + HX_OFF);
    float* hy   = (float*)(ws + HY_OFF);
    float* a_raw = (float*)(ws + A_OFF);
    float* b_raw = (float*)(ws + B_OFF);
    float* t1    = (float*)(ws + T1_OFF);

    // zero the accumulators every call (harness does not re-poison between replays)
    hipMemsetAsync(ws + A_OFF, 0, 2 * 262144 + 64, stream);

    prep_kernel<<<dim3(NN, 2), 256, 0, stream>>>(X, Y, Xb, Yb, hx, hy);
    hsic_main<<<1024, 256, 0, stream>>>(Xb, Yb, hx, hy, a_raw, b_raw, t1);
    finalize_kernel<<<1, 256, 0, stream>>>(a_raw, b_raw, t1, out);
}

// Round 2
// 220.374 us; speedup vs baseline: 1.9744x; 1.9744x over previous
//
#include <hip/hip_runtime.h>
#include <hip/hip_bf16.h>

typedef __attribute__((ext_vector_type(8))) short bf16x8;
typedef __attribute__((ext_vector_type(4))) float f32x4;

#define NN 4096
#define DD 64
#define LL 16
// sqrt(log2(e)): scaling x by this makes dot(xs,xs') = log2(e)*dot(x,x'),
// so K = exp(dot - hi - hj) becomes exp2(dots - hsi - hsj) -> bare v_exp_f32.
#define SCALE 1.2011224087864498f

__device__ __forceinline__ ushort f2bf(float f) {
    unsigned int u = __float_as_uint(f);
    unsigned int r = u + 0x7FFFu + ((u >> 16) & 1u);
    return (ushort)(r >> 16);
}
__device__ __forceinline__ float bf2f(ushort u) {
    return __uint_as_float(((unsigned int)u) << 16);
}

__device__ __forceinline__ void gload_lds16(const void* g, void* l) {
    __builtin_amdgcn_global_load_lds((const __attribute__((address_space(1))) unsigned int*)g,
                                     (__attribute__((address_space(3))) unsigned int*)l, 16, 0, 0);
}
__device__ __forceinline__ void gload_lds4(const void* g, void* l) {
    __builtin_amdgcn_global_load_lds((const __attribute__((address_space(1))) unsigned int*)g,
                                     (__attribute__((address_space(3))) unsigned int*)l, 4, 0, 0);
}

// Transpose (N,D,L) fp32 -> (L,N,D) bf16 with per-row 16B-chunk XOR swizzle
// (chunk co of row n stored at position co ^ (n&7)), values prescaled by SCALE,
// and h[l][n] = 0.5 * sum_d xs_bf16^2 (fp32, from the SAME bf16 values the MFMA sees).
__global__ void prep_kernel(const float* __restrict__ X, const float* __restrict__ Y,
                            ushort* __restrict__ Xb, ushort* __restrict__ Yb,
                            float* __restrict__ hx, float* __restrict__ hy) {
    const float* in = blockIdx.y ? Y : X;
    ushort* outb    = blockIdx.y ? Yb : Xb;
    float* h        = blockIdx.y ? hy : hx;

    __shared__ float lds[64 * 17];
    __shared__ float psum[16][17];

    int n = blockIdx.x;
    int t = threadIdx.x;            // 256 threads
    const float* row = in + (size_t)n * (DD * LL);   // (d,l) l-fastest

#pragma unroll
    for (int r = 0; r < 4; ++r) {
        int e = t + r * 256;        // e = d*16 + l
        lds[(e >> 4) * 17 + (e & 15)] = row[e];
    }
    __syncthreads();

    int l = t >> 4, c = t & 15;     // thread handles (l, d = c*4..c*4+3)
    float p = 0.f;
    ushort4 w;
    {
        float v0 = lds[(c * 4 + 0) * 17 + l] * SCALE;
        float v1 = lds[(c * 4 + 1) * 17 + l] * SCALE;
        float v2 = lds[(c * 4 + 2) * 17 + l] * SCALE;
        float v3 = lds[(c * 4 + 3) * 17 + l] * SCALE;
        ushort u0 = f2bf(v0), u1 = f2bf(v1), u2 = f2bf(v2), u3 = f2bf(v3);
        float b0 = bf2f(u0), b1 = bf2f(u1), b2 = bf2f(u2), b3 = bf2f(u3);
        p = b0 * b0 + b1 * b1 + b2 * b2 + b3 * b3;
        w.x = u0; w.y = u1; w.z = u2; w.w = u3;
    }
    // swizzled chunk position: chunk co = c>>1 (16B), half = c&1 (8B)
    int cs = (c >> 1) ^ (n & 7);
    *reinterpret_cast<ushort4*>(outb + ((size_t)l * NN + n) * DD + cs * 8 + (c & 1) * 4) = w;

    psum[l][c] = p;
    __syncthreads();
    if (t < 16) {
        float s = 0.f;
#pragma unroll
        for (int i = 0; i < 16; ++i) s += psum[t][i];
        h[t * NN + n] = 0.5f * s;
    }
}

// LDS buffer: 2 x 8448 bytes. Per buffer: [mat(2)][row32(32)][128B swizzled] + 256B of h (hx[32], hy[32]).
#define BUF_BYTES 8448
#define H_OFF 8192

__device__ __forceinline__ void stage_tile(ushort* smem, int buf, int wave, int lane,
                                           const ushort* __restrict__ Xl, const ushort* __restrict__ Yl,
                                           const float* __restrict__ hxl, const float* __restrict__ hyl,
                                           int jb) {
    char* base = (char*)smem + buf * BUF_BYTES;
    const ushort* mat = (wave < 2) ? Xl : Yl;
#pragma unroll
    for (int q = 0; q < 2; ++q) {
        int ridx = wave * 2 + q;                       // 0..7 -> mat*4 + rowgroup
        int rbase = (ridx & 3) * 8;
        const ushort* src = mat + (size_t)(jb + rbase + (lane >> 3)) * DD + (lane & 7) * 8;
        gload_lds16(src, base + ridx * 1024);
    }
    if (wave == 0) {
        const float* hsrc = (lane < 32) ? (hxl + jb + lane) : (hyl + jb + (lane - 32));
        gload_lds4(hsrc, base + H_OFF);
    }
}

__global__ __launch_bounds__(256) void hsic_main(
    const ushort* __restrict__ Xb, const ushort* __restrict__ Yb,
    const float* __restrict__ hx, const float* __restrict__ hy,
    float* __restrict__ a_raw, float* __restrict__ b_raw, float* __restrict__ t1) {

    int blk = blockIdx.x;               // 2048 blocks: l(16) x itile(32) x jc(4)
    int l = blk >> 7;
    int r = blk & 127;
    int itile = r >> 2;
    int jc = r & 3;

    int wave = threadIdx.x >> 6;
    int lane = threadIdx.x & 63;
    int lrow = lane & 15;
    int khi  = lane >> 4;

    int ibase = itile * 128 + wave * 32;
    int jcbase = jc * 1024;

    const ushort* Xl = Xb + (size_t)l * (NN * DD);
    const ushort* Yl = Yb + (size_t)l * (NN * DD);
    const float* hxl = hx + l * NN;
    const float* hyl = hy + l * NN;

    __shared__ __align__(16) ushort smem[2 * BUF_BYTES / 2];

    // A fragments (swizzled global layout) + negated h_i, fixed for the whole j loop
    bf16x8 ax[2][2], ay[2][2];
    float nhxi[2][4], nhyi[2][4];
#pragma unroll
    for (int rg = 0; rg < 2; ++rg) {
        int arow = ibase + rg * 16 + lrow;
#pragma unroll
        for (int kc = 0; kc < 2; ++kc) {
            int cs = (kc * 4 + khi) ^ (arow & 7);
            ax[rg][kc] = *reinterpret_cast<const bf16x8*>(Xl + (size_t)arow * DD + cs * 8);
            ay[rg][kc] = *reinterpret_cast<const bf16x8*>(Yl + (size_t)arow * DD + cs * 8);
        }
        int crow = ibase + rg * 16 + khi * 4;
#pragma unroll
        for (int q = 0; q < 4; ++q) {
            nhxi[rg][q] = -hxl[crow + q];
            nhyi[rg][q] = -hyl[crow + q];
        }
    }

    // per-lane LDS byte offsets for B fragments (constant across iterations)
    int offb[2][2];
#pragma unroll
    for (int cg = 0; cg < 2; ++cg)
#pragma unroll
        for (int kc = 0; kc < 2; ++kc)
            offb[cg][kc] = (cg * 16 + lrow) * 128 + (((kc * 4 + khi) ^ (lrow & 7)) * 16);

    float rpx[2][4] = {}, rpy[2][4] = {};
    float t1a[4] = {};

    stage_tile(smem, 0, wave, lane, Xl, Yl, hxl, hyl, jcbase);
    __syncthreads();

    int cur = 0;
    for (int jt = 0; jt < 32; ++jt) {
        if (jt + 1 < 32)
            stage_tile(smem, cur ^ 1, wave, lane, Xl, Yl, hxl, hyl, jcbase + (jt + 1) * 32);

        const char* bufc = (const char*)smem + cur * BUF_BYTES;
        const float* hbuf = (const float*)(bufc + H_OFF);

        float hxj[2], hyj[2];
#pragma unroll
        for (int cg = 0; cg < 2; ++cg) {
            hxj[cg] = hbuf[cg * 16 + lrow];
            hyj[cg] = hbuf[32 + cg * 16 + lrow];
        }

        // init accumulators with -(h_i + h_j): MFMA result is then the full base-2 exponent
        f32x4 gx[2][2], gy[2][2];
#pragma unroll
        for (int rg = 0; rg < 2; ++rg)
#pragma unroll
            for (int cg = 0; cg < 2; ++cg)
#pragma unroll
                for (int q = 0; q < 4; ++q) {
                    gx[rg][cg][q] = nhxi[rg][q] - hxj[cg];
                    gy[rg][cg][q] = nhyi[rg][q] - hyj[cg];
                }

        bf16x8 bfx[2][2], bfy[2][2];
#pragma unroll
        for (int cg = 0; cg < 2; ++cg)
#pragma unroll
            for (int kc = 0; kc < 2; ++kc) {
                bfx[cg][kc] = *reinterpret_cast<const bf16x8*>(bufc + offb[cg][kc]);
                bfy[cg][kc] = *reinterpret_cast<const bf16x8*>(bufc + 4096 + offb[cg][kc]);
            }

#pragma unroll
        for (int rg = 0; rg < 2; ++rg)
#pragma unroll
            for (int cg = 0; cg < 2; ++cg)
#pragma unroll
                for (int kc = 0; kc < 2; ++kc) {
                    gx[rg][cg] = __builtin_amdgcn_mfma_f32_16x16x32_bf16(ax[rg][kc], bfx[cg][kc], gx[rg][cg], 0, 0, 0);
                    gy[rg][cg] = __builtin_amdgcn_mfma_f32_16x16x32_bf16(ay[rg][kc], bfy[cg][kc], gy[rg][cg], 0, 0, 0);
                }

#pragma unroll
        for (int rg = 0; rg < 2; ++rg)
#pragma unroll
            for (int cg = 0; cg < 2; ++cg)
#pragma unroll
                for (int q = 0; q < 4; ++q) {
                    float kxv = __builtin_exp2f(gx[rg][cg][q]);
                    float kyv = __builtin_exp2f(gy[rg][cg][q]);
                    rpx[rg][q] += kxv;
                    rpy[rg][q] += kyv;
                    t1a[rg * 2 + cg] = __builtin_fmaf(kxv, kyv, t1a[rg * 2 + cg]);
                }

        __syncthreads();
        cur ^= 1;
    }

    // row-sum reduce across the 16 lanes sharing a C-row
#pragma unroll
    for (int rg = 0; rg < 2; ++rg)
#pragma unroll
        for (int q = 0; q < 4; ++q) {
            float vx = rpx[rg][q], vy = rpy[rg][q];
#pragma unroll
            for (int s = 1; s < 16; s <<= 1) {
                vx += __shfl_xor(vx, s);
                vy += __shfl_xor(vy, s);
            }
            if (lrow == 0) {
                int row = ibase + rg * 16 + khi * 4 + q;
                atomicAdd(&a_raw[l * NN + row], vx);
                atomicAdd(&b_raw[l * NN + row], vy);
            }
        }

    float v = t1a[0] + t1a[1] + t1a[2] + t1a[3];
#pragma unroll
    for (int s = 1; s < 64; s <<= 1) v += __shfl_xor(v, s);
    if (lane == 0) atomicAdd(&t1[l], v);
}

// One block per l; S_l = T1 - (2/n) sum A_i B_i + (sum A)(sum B)/n^2; atomicAdd into out.
__global__ void finalize_kernel(const float* __restrict__ a_raw, const float* __restrict__ b_raw,
                                const float* __restrict__ t1, float* __restrict__ out) {
    int l = blockIdx.x;
    int t = threadIdx.x;
    int lane = t & 63, w = t >> 6;

    float sab = 0.f, sa = 0.f, sb = 0.f;
    for (int i = t; i < NN; i += 256) {
        float av = a_raw[l * NN + i], bv = b_raw[l * NN + i];
        sab = __builtin_fmaf(av, bv, sab);
        sa += av;
        sb += bv;
    }
#pragma unroll
    for (int s = 1; s < 64; s <<= 1) {
        sab += __shfl_xor(sab, s);
        sa  += __shfl_xor(sa, s);
        sb  += __shfl_xor(sb, s);
    }
    __shared__ float sh[3][4];
    if (lane == 0) { sh[0][w] = sab; sh[1][w] = sa; sh[2][w] = sb; }
    __syncthreads();
    if (t == 0) {
        float rab = sh[0][0] + sh[0][1] + sh[0][2] + sh[0][3];
        float ra  = sh[1][0] + sh[1][1] + sh[1][2] + sh[1][3];
        float rb  = sh[2][0] + sh[2][1] + sh[2][2] + sh[2][3];
        const float n = (float)NN;
        float S = t1[l] - (2.f / n) * rab + (ra * rb) / (n * n);
        atomicAdd(out, S / (4095.f * 4095.f));
    }
}

extern "C" void kernel_launch(void* const* d_in, const int* in_sizes, int n_in,
                              void* d_out, int out_size, void* d_ws, size_t ws_size,
                              hipStream_t stream) {
    const float* X = (const float*)d_in[0];
    const float* Y = (const float*)d_in[1];
    float* out = (float*)d_out;
    char* ws = (char*)d_ws;

    const size_t XB_OFF  = 0;                       // L*N*D bf16 = 8388608 B
    const size_t YB_OFF  = 8388608;
    const size_t HX_OFF  = 16777216;                // L*N fp32
    const size_t HY_OFF  = 17039360;
    const size_t A_OFF   = 17301504;                // L*N fp32
    const size_t B_OFF   = 17563648;
    const size_t T1_OFF  = 17825792;                // L fp32

    ushort* Xb  = (ushort*)(ws + XB_OFF);
    ushort* Yb  = (ushort*)(ws + YB_OFF);
    float* hx   = (float*)(ws + HX_OFF);
    float* hy   = (float*)(ws + HY_OFF);
    float* a_raw = (float*)(ws + A_OFF);
    float* b_raw = (float*)(ws + B_OFF);
    float* t1    = (float*)(ws + T1_OFF);

    hipMemsetAsync(ws + A_OFF, 0, 2 * 262144 + 64, stream);
    hipMemsetAsync(d_out, 0, sizeof(float), stream);

    prep_kernel<<<dim3(NN, 2), 256, 0, stream>>>(X, Y, Xb, Yb, hx, hy);
    hsic_main<<<2048, 256, 0, stream>>>(Xb, Yb, hx, hy, a_raw, b_raw, t1);
    finalize_kernel<<<LL, 256, 0, stream>>>(a_raw, b_raw, t1, out);
}

// Round 3
// 168.844 us; speedup vs baseline: 2.5770x; 1.3052x over previous
//
#include <hip/hip_runtime.h>
#include <hip/hip_bf16.h>

typedef __attribute__((ext_vector_type(8))) short bf16x8;
typedef __attribute__((ext_vector_type(4))) float f32x4;

#define NN 4096
#define DD 64
#define LL 16
// sqrt(log2(e)): scaling x by this makes dot(xs,xs') = log2(e)*dot(x,x'),
// so K = exp(dot - hi - hj) becomes exp2(dots - hsi - hsj) -> bare v_exp_f32.
#define SCALE 1.2011224087864498f
// subtile skip threshold (base-2 exponent). Skipped terms <= 2^-24 each;
// expected aggregate ~1e-8 vs output ~4e-3 and threshold 7.8e-5.
#define THR -24.0f

__device__ __forceinline__ ushort f2bf(float f) {
    unsigned int u = __float_as_uint(f);
    unsigned int r = u + 0x7FFFu + ((u >> 16) & 1u);
    return (ushort)(r >> 16);
}
__device__ __forceinline__ float bf2f(ushort u) {
    return __uint_as_float(((unsigned int)u) << 16);
}

__device__ __forceinline__ void gload_lds16(const void* g, void* l) {
    __builtin_amdgcn_global_load_lds((const __attribute__((address_space(1))) unsigned int*)g,
                                     (__attribute__((address_space(3))) unsigned int*)l, 16, 0, 0);
}
__device__ __forceinline__ void gload_lds4(const void* g, void* l) {
    __builtin_amdgcn_global_load_lds((const __attribute__((address_space(1))) unsigned int*)g,
                                     (__attribute__((address_space(3))) unsigned int*)l, 4, 0, 0);
}

// Transpose (N,D,L) fp32 -> (L,N,D) bf16 with per-row 16B-chunk XOR swizzle
// (chunk co of row n stored at position co ^ (n&7)), values prescaled by SCALE,
// and h[l][n] = 0.5 * sum_d xs_bf16^2 (fp32, from the SAME bf16 values the MFMA sees).
__global__ void prep_kernel(const float* __restrict__ X, const float* __restrict__ Y,
                            ushort* __restrict__ Xb, ushort* __restrict__ Yb,
                            float* __restrict__ hx, float* __restrict__ hy) {
    const float* in = blockIdx.y ? Y : X;
    ushort* outb    = blockIdx.y ? Yb : Xb;
    float* h        = blockIdx.y ? hy : hx;

    __shared__ float lds[64 * 17];
    __shared__ float psum[16][17];

    int n = blockIdx.x;
    int t = threadIdx.x;            // 256 threads
    const float* row = in + (size_t)n * (DD * LL);   // (d,l) l-fastest

#pragma unroll
    for (int r = 0; r < 4; ++r) {
        int e = t + r * 256;        // e = d*16 + l
        lds[(e >> 4) * 17 + (e & 15)] = row[e];
    }
    __syncthreads();

    int l = t >> 4, c = t & 15;     // thread handles (l, d = c*4..c*4+3)
    float p = 0.f;
    ushort4 w;
    {
        float v0 = lds[(c * 4 + 0) * 17 + l] * SCALE;
        float v1 = lds[(c * 4 + 1) * 17 + l] * SCALE;
        float v2 = lds[(c * 4 + 2) * 17 + l] * SCALE;
        float v3 = lds[(c * 4 + 3) * 17 + l] * SCALE;
        ushort u0 = f2bf(v0), u1 = f2bf(v1), u2 = f2bf(v2), u3 = f2bf(v3);
        float b0 = bf2f(u0), b1 = bf2f(u1), b2 = bf2f(u2), b3 = bf2f(u3);
        p = b0 * b0 + b1 * b1 + b2 * b2 + b3 * b3;
        w.x = u0; w.y = u1; w.z = u2; w.w = u3;
    }
    int cs = (c >> 1) ^ (n & 7);
    *reinterpret_cast<ushort4*>(outb + ((size_t)l * NN + n) * DD + cs * 8 + (c & 1) * 4) = w;

    psum[l][c] = p;
    __syncthreads();
    if (t < 16) {
        float s = 0.f;
#pragma unroll
        for (int i = 0; i < 16; ++i) s += psum[t][i];
        h[t * NN + n] = 0.5f * s;
    }
}

// LDS buffer: 2 x 8448 bytes. Per buffer: [mat(2)][row32(32)][128B swizzled] + 256B of h (hx[32], hy[32]).
#define BUF_BYTES 8448
#define H_OFF 8192

__device__ __forceinline__ void stage_tile(ushort* smem, int buf, int wave, int lane,
                                           const ushort* __restrict__ Xl, const ushort* __restrict__ Yl,
                                           const float* __restrict__ hxl, const float* __restrict__ hyl,
                                           int jb) {
    char* base = (char*)smem + buf * BUF_BYTES;
    const ushort* mat = (wave < 2) ? Xl : Yl;
#pragma unroll
    for (int q = 0; q < 2; ++q) {
        int ridx = wave * 2 + q;                       // 0..7 -> mat*4 + rowgroup
        int rbase = (ridx & 3) * 8;
        const ushort* src = mat + (size_t)(jb + rbase + (lane >> 3)) * DD + (lane & 7) * 8;
        gload_lds16(src, base + ridx * 1024);
    }
    if (wave == 0) {
        const float* hsrc = (lane < 32) ? (hxl + jb + lane) : (hyl + jb + (lane - 32));
        gload_lds4(hsrc, base + H_OFF);
    }
}

__global__ __launch_bounds__(256) void hsic_main(
    const ushort* __restrict__ Xb, const ushort* __restrict__ Yb,
    const float* __restrict__ hx, const float* __restrict__ hy,
    float* __restrict__ a_raw, float* __restrict__ b_raw, float* __restrict__ t1) {

    int blk = blockIdx.x;               // 2048 blocks: l(16) x itile(32) x jc(4)
    int l = blk >> 7;
    int r = blk & 127;
    int itile = r >> 2;
    int jc = r & 3;

    int wave = threadIdx.x >> 6;
    int lane = threadIdx.x & 63;
    int lrow = lane & 15;
    int khi  = lane >> 4;

    int ibase = itile * 128 + wave * 32;
    int jcbase = jc * 1024;

    const ushort* Xl = Xb + (size_t)l * (NN * DD);
    const ushort* Yl = Yb + (size_t)l * (NN * DD);
    const float* hxl = hx + l * NN;
    const float* hyl = hy + l * NN;

    __shared__ __align__(16) ushort smem[2 * BUF_BYTES / 2];

    // A fragments (swizzled global layout) + negated h_i (vectorized), fixed for the whole j loop
    bf16x8 ax[2][2], ay[2][2];
    f32x4 nhxi4[2], nhyi4[2];
#pragma unroll
    for (int rg = 0; rg < 2; ++rg) {
        int arow = ibase + rg * 16 + lrow;
#pragma unroll
        for (int kc = 0; kc < 2; ++kc) {
            int cs = (kc * 4 + khi) ^ (arow & 7);
            ax[rg][kc] = *reinterpret_cast<const bf16x8*>(Xl + (size_t)arow * DD + cs * 8);
            ay[rg][kc] = *reinterpret_cast<const bf16x8*>(Yl + (size_t)arow * DD + cs * 8);
        }
        int crow = ibase + rg * 16 + khi * 4;
#pragma unroll
        for (int q = 0; q < 4; ++q) {
            nhxi4[rg][q] = -hxl[crow + q];
            nhyi4[rg][q] = -hyl[crow + q];
        }
    }

    // per-lane LDS byte offsets for B fragments (constant across iterations)
    int offb[2][2];
#pragma unroll
    for (int cg = 0; cg < 2; ++cg)
#pragma unroll
        for (int kc = 0; kc < 2; ++kc)
            offb[cg][kc] = (cg * 16 + lrow) * 128 + (((kc * 4 + khi) ^ (lrow & 7)) * 16);

    float rpx[2][4] = {}, rpy[2][4] = {};
    float t1a[4] = {};

    stage_tile(smem, 0, wave, lane, Xl, Yl, hxl, hyl, jcbase);
    __syncthreads();

    int cur = 0;
    for (int jt = 0; jt < 32; ++jt) {
        if (jt + 1 < 32)
            stage_tile(smem, cur ^ 1, wave, lane, Xl, Yl, hxl, hyl, jcbase + (jt + 1) * 32);

        const char* bufc = (const char*)smem + cur * BUF_BYTES;
        const float* hbuf = (const float*)(bufc + H_OFF);

        float hxj[2], hyj[2];
#pragma unroll
        for (int cg = 0; cg < 2; ++cg) {
            hxj[cg] = hbuf[cg * 16 + lrow];
            hyj[cg] = hbuf[32 + cg * 16 + lrow];
        }

        bf16x8 bfx[2][2], bfy[2][2];
#pragma unroll
        for (int cg = 0; cg < 2; ++cg)
#pragma unroll
            for (int kc = 0; kc < 2; ++kc) {
                bfx[cg][kc] = *reinterpret_cast<const bf16x8*>(bufc + offb[cg][kc]);
                bfy[cg][kc] = *reinterpret_cast<const bf16x8*>(bufc + 4096 + offb[cg][kc]);
            }

        // C init = -(h_i + h_j) (vector sub -> v_pk_add_f32); MFMA output is the base-2 exponent
        f32x4 gx[2][2], gy[2][2];
#pragma unroll
        for (int rg = 0; rg < 2; ++rg)
#pragma unroll
            for (int cg = 0; cg < 2; ++cg) {
                gx[rg][cg] = nhxi4[rg] - hxj[cg];
                gy[rg][cg] = nhyi4[rg] - hyj[cg];
            }

#pragma unroll
        for (int rg = 0; rg < 2; ++rg)
#pragma unroll
            for (int cg = 0; cg < 2; ++cg)
#pragma unroll
                for (int kc = 0; kc < 2; ++kc) {
                    gx[rg][cg] = __builtin_amdgcn_mfma_f32_16x16x32_bf16(ax[rg][kc], bfx[cg][kc], gx[rg][cg], 0, 0, 0);
                    gy[rg][cg] = __builtin_amdgcn_mfma_f32_16x16x32_bf16(ay[rg][kc], bfy[cg][kc], gy[rg][cg], 0, 0, 0);
                }

        // per-subtile wave-uniform skip: everything except (near-)diagonal subtiles
        // has exponent < -24 -> contributes < 2^-24 each, aggregate ~1e-8. Skip epilogue.
#pragma unroll
        for (int rg = 0; rg < 2; ++rg)
#pragma unroll
            for (int cg = 0; cg < 2; ++cg) {
                float mx = fmaxf(fmaxf(gx[rg][cg][0], gx[rg][cg][1]), fmaxf(gx[rg][cg][2], gx[rg][cg][3]));
                float my = fmaxf(fmaxf(gy[rg][cg][0], gy[rg][cg][1]), fmaxf(gy[rg][cg][2], gy[rg][cg][3]));
                if (__any(fmaxf(mx, my) >= THR)) {
#pragma unroll
                    for (int q = 0; q < 4; ++q) {
                        float kxv = __builtin_exp2f(gx[rg][cg][q]);
                        float kyv = __builtin_exp2f(gy[rg][cg][q]);
                        rpx[rg][q] += kxv;
                        rpy[rg][q] += kyv;
                        t1a[rg * 2 + cg] = __builtin_fmaf(kxv, kyv, t1a[rg * 2 + cg]);
                    }
                }
            }

        __syncthreads();
        cur ^= 1;
    }

    // row-sum reduce across the 16 lanes sharing a C-row
#pragma unroll
    for (int rg = 0; rg < 2; ++rg)
#pragma unroll
        for (int q = 0; q < 4; ++q) {
            float vx = rpx[rg][q], vy = rpy[rg][q];
#pragma unroll
            for (int s = 1; s < 16; s <<= 1) {
                vx += __shfl_xor(vx, s);
                vy += __shfl_xor(vy, s);
            }
            if (lrow == 0) {
                int row = ibase + rg * 16 + khi * 4 + q;
                atomicAdd(&a_raw[l * NN + row], vx);
                atomicAdd(&b_raw[l * NN + row], vy);
            }
        }

    float v = t1a[0] + t1a[1] + t1a[2] + t1a[3];
#pragma unroll
    for (int s = 1; s < 64; s <<= 1) v += __shfl_xor(v, s);
    if (lane == 0) atomicAdd(&t1[l], v);
}

// One block per l; S_l = T1 - (2/n) sum A_i B_i + (sum A)(sum B)/n^2; atomicAdd into out.
__global__ void finalize_kernel(const float* __restrict__ a_raw, const float* __restrict__ b_raw,
                                const float* __restrict__ t1, float* __restrict__ out) {
    int l = blockIdx.x;
    int t = threadIdx.x;
    int lane = t & 63, w = t >> 6;

    float sab = 0.f, sa = 0.f, sb = 0.f;
    for (int i = t; i < NN; i += 256) {
        float av = a_raw[l * NN + i], bv = b_raw[l * NN + i];
        sab = __builtin_fmaf(av, bv, sab);
        sa += av;
        sb += bv;
    }
#pragma unroll
    for (int s = 1; s < 64; s <<= 1) {
        sab += __shfl_xor(sab, s);
        sa  += __shfl_xor(sa, s);
        sb  += __shfl_xor(sb, s);
    }
    __shared__ float sh[3][4];
    if (lane == 0) { sh[0][w] = sab; sh[1][w] = sa; sh[2][w] = sb; }
    __syncthreads();
    if (t == 0) {
        float rab = sh[0][0] + sh[0][1] + sh[0][2] + sh[0][3];
        float ra  = sh[1][0] + sh[1][1] + sh[1][2] + sh[1][3];
        float rb  = sh[2][0] + sh[2][1] + sh[2][2] + sh[2][3];
        const float n = (float)NN;
        float S = t1[l] - (2.f / n) * rab + (ra * rb) / (n * n);
        atomicAdd(out, S / (4095.f * 4095.f));
    }
}

extern "C" void kernel_launch(void* const* d_in, const int* in_sizes, int n_in,
                              void* d_out, int out_size, void* d_ws, size_t ws_size,
                              hipStream_t stream) {
    const float* X = (const float*)d_in[0];
    const float* Y = (const float*)d_in[1];
    float* out = (float*)d_out;
    char* ws = (char*)d_ws;

    const size_t XB_OFF  = 0;                       // L*N*D bf16 = 8388608 B
    const size_t YB_OFF  = 8388608;
    const size_t HX_OFF  = 16777216;                // L*N fp32
    const size_t HY_OFF  = 17039360;
    const size_t A_OFF   = 17301504;                // L*N fp32
    const size_t B_OFF   = 17563648;
    const size_t T1_OFF  = 17825792;                // L fp32

    ushort* Xb  = (ushort*)(ws + XB_OFF);
    ushort* Yb  = (ushort*)(ws + YB_OFF);
    float* hx   = (float*)(ws + HX_OFF);
    float* hy   = (float*)(ws + HY_OFF);
    float* a_raw = (float*)(ws + A_OFF);
    float* b_raw = (float*)(ws + B_OFF);
    float* t1    = (float*)(ws + T1_OFF);

    hipMemsetAsync(ws + A_OFF, 0, 2 * 262144 + 64, stream);
    hipMemsetAsync(d_out, 0, sizeof(float), stream);

    prep_kernel<<<dim3(NN, 2), 256, 0, stream>>>(X, Y, Xb, Yb, hx, hy);
    hsic_main<<<2048, 256, 0, stream>>>(Xb, Yb, hx, hy, a_raw, b_raw, t1);
    finalize_kernel<<<LL, 256, 0, stream>>>(a_raw, b_raw, t1, out);
}

// Round 4
// 113.909 us; speedup vs baseline: 3.8198x; 1.4823x over previous
//
#include <hip/hip_runtime.h>
#include <hip/hip_bf16.h>

typedef __attribute__((ext_vector_type(8))) short bf16x8;
typedef __attribute__((ext_vector_type(4))) float f32x4;

#define NN 4096
#define DD 64
#define LL 16
// sqrt(log2(e)): prescaling x by this makes dot = log2(e)*<x,x'>, so
// K = exp(dot - hi - hj) becomes exp2(dots - hsi - hsj) -> bare v_exp_f32.
#define SCALE 1.2011224087864498f
// skip threshold (base-2 exponent): skipped terms <= 2^-24 each.
#define THR -24.0f

__device__ __forceinline__ ushort f2bf(float f) {
    unsigned int u = __float_as_uint(f);
    unsigned int r = u + 0x7FFFu + ((u >> 16) & 1u);
    return (ushort)(r >> 16);
}
__device__ __forceinline__ float bf2f(ushort u) {
    return __uint_as_float(((unsigned int)u) << 16);
}

__device__ __forceinline__ void gload_lds16(const void* g, void* l) {
    __builtin_amdgcn_global_load_lds((const __attribute__((address_space(1))) unsigned int*)g,
                                     (__attribute__((address_space(3))) unsigned int*)l, 16, 0, 0);
}
__device__ __forceinline__ void gload_lds4(const void* g, void* l) {
    __builtin_amdgcn_global_load_lds((const __attribute__((address_space(1))) unsigned int*)g,
                                     (__attribute__((address_space(3))) unsigned int*)l, 4, 0, 0);
}

// Transpose (N,D,L) fp32 -> (L,N,D) bf16 with per-row 16B-chunk XOR swizzle
// (chunk co of row n stored at co ^ (n&7)), values prescaled by SCALE, and
// h[l][n] = 0.5 * sum_d xs_bf16^2 (fp32, from the SAME bf16 values MFMA sees).
__global__ void prep_kernel(const float* __restrict__ X, const float* __restrict__ Y,
                            ushort* __restrict__ Xb, ushort* __restrict__ Yb,
                            float* __restrict__ hx, float* __restrict__ hy) {
    const float* in = blockIdx.y ? Y : X;
    ushort* outb    = blockIdx.y ? Yb : Xb;
    float* h        = blockIdx.y ? hy : hx;

    __shared__ float lds[64 * 17];
    __shared__ float psum[16][17];

    int n = blockIdx.x;
    int t = threadIdx.x;
    const float* row = in + (size_t)n * (DD * LL);

#pragma unroll
    for (int r = 0; r < 4; ++r) {
        int e = t + r * 256;        // e = d*16 + l
        lds[(e >> 4) * 17 + (e & 15)] = row[e];
    }
    __syncthreads();

    int l = t >> 4, c = t & 15;
    float p = 0.f;
    ushort4 w;
    {
        float v0 = lds[(c * 4 + 0) * 17 + l] * SCALE;
        float v1 = lds[(c * 4 + 1) * 17 + l] * SCALE;
        float v2 = lds[(c * 4 + 2) * 17 + l] * SCALE;
        float v3 = lds[(c * 4 + 3) * 17 + l] * SCALE;
        ushort u0 = f2bf(v0), u1 = f2bf(v1), u2 = f2bf(v2), u3 = f2bf(v3);
        float b0 = bf2f(u0), b1 = bf2f(u1), b2 = bf2f(u2), b3 = bf2f(u3);
        p = b0 * b0 + b1 * b1 + b2 * b2 + b3 * b3;
        w.x = u0; w.y = u1; w.z = u2; w.w = u3;
    }
    int cs = (c >> 1) ^ (n & 7);
    *reinterpret_cast<ushort4*>(outb + ((size_t)l * NN + n) * DD + cs * 8 + (c & 1) * 4) = w;

    psum[l][c] = p;
    __syncthreads();
    if (t < 16) {
        float s = 0.f;
#pragma unroll
        for (int i = 0; i < 16; ++i) s += psum[t][i];
        h[t * NN + n] = 0.5f * s;
    }
}

// LDS: 2 x 8448 B. Per buffer: [mat(2)][row32(32)][128B swizzled] + 256B h (hx[32], hy[32]).
#define BUF_BYTES 8448
#define H_OFF 8192

__device__ __forceinline__ void stage_tile(ushort* smem, int buf, int wave, int lane,
                                           const ushort* __restrict__ Xl, const ushort* __restrict__ Yl,
                                           const float* __restrict__ hxl, const float* __restrict__ hyl,
                                           int jb) {
    char* base = (char*)smem + buf * BUF_BYTES;
    const ushort* mat = (wave < 2) ? Xl : Yl;
#pragma unroll
    for (int q = 0; q < 2; ++q) {
        int ridx = wave * 2 + q;
        int rbase = (ridx & 3) * 8;
        const ushort* src = mat + (size_t)(jb + rbase + (lane >> 3)) * DD + (lane & 7) * 8;
        gload_lds16(src, base + ridx * 1024);
    }
    if (wave == 0) {
        const float* hsrc = (lane < 32) ? (hxl + jb + lane) : (hyl + jb + (lane - 32));
        gload_lds4(hsrc, base + H_OFF);
    }
}

// Triangular fused kernel. Grid = 16 l x 16 pairs x 4 segments = 1024 blocks.
// Pair p owns i-tiles {p, 31-p} (128 rows each); concatenated j-tile list
// (jt>=4*ti for each, 132 units total) split into 4 segments of 33.
// Band units (jt < 4*ti+4) cover the diagonal 128x128 block fully: weight 1,
// row sums only. Strict-upper units: weight 2 for T1, col sums mirror to rows.
__global__ __launch_bounds__(256) void hsic_tri(
    const ushort* __restrict__ Xb, const ushort* __restrict__ Yb,
    const float* __restrict__ hx, const float* __restrict__ hy,
    float* __restrict__ a_raw, float* __restrict__ b_raw, float* __restrict__ t1) {

    int blk = blockIdx.x;
    int l = blk >> 6;
    int p = (blk >> 2) & 15;
    int s = blk & 3;
    int u0 = s * 33, u1 = u0 + 33;
    int c = 128 - 4 * p;                 // units in phase A (ti = p)

    int wave = threadIdx.x >> 6;
    int lane = threadIdx.x & 63;
    int lrow = lane & 15;
    int khi  = lane >> 4;

    const ushort* Xl = Xb + (size_t)l * (NN * DD);
    const ushort* Yl = Yb + (size_t)l * (NN * DD);
    const float* hxl = hx + l * NN;
    const float* hyl = hy + l * NN;

    __shared__ __align__(16) ushort smem[2 * BUF_BYTES / 2];

    float t1_1 = 0.f, t1_2 = 0.f;        // band (x1) and strict-upper (x2) T1 partials

    auto run_phase = [&](int ti, int jt0, int cnt) {
        int ibase = ti * 128 + wave * 32;

        bf16x8 ax[2][2], ay[2][2];
        f32x4 nhxi4[2], nhyi4[2];
#pragma unroll
        for (int rg = 0; rg < 2; ++rg) {
            int arow = ibase + rg * 16 + lrow;
#pragma unroll
            for (int kc = 0; kc < 2; ++kc) {
                int cs = (kc * 4 + khi) ^ (arow & 7);
                ax[rg][kc] = *reinterpret_cast<const bf16x8*>(Xl + (size_t)arow * DD + cs * 8);
                ay[rg][kc] = *reinterpret_cast<const bf16x8*>(Yl + (size_t)arow * DD + cs * 8);
            }
            int crow = ibase + rg * 16 + khi * 4;
#pragma unroll
            for (int q = 0; q < 4; ++q) {
                nhxi4[rg][q] = -hxl[crow + q];
                nhyi4[rg][q] = -hyl[crow + q];
            }
        }

        int offb[2][2];
#pragma unroll
        for (int cg = 0; cg < 2; ++cg)
#pragma unroll
            for (int kc = 0; kc < 2; ++kc)
                offb[cg][kc] = (cg * 16 + lrow) * 128 + (((kc * 4 + khi) ^ (lrow & 7)) * 16);

        float rpx[2][4] = {}, rpy[2][4] = {};

        stage_tile(smem, 0, wave, lane, Xl, Yl, hxl, hyl, jt0 * 32);
        __syncthreads();

        int cur = 0;
        for (int k = 0; k < cnt; ++k) {
            if (k + 1 < cnt)
                stage_tile(smem, cur ^ 1, wave, lane, Xl, Yl, hxl, hyl, (jt0 + k + 1) * 32);

            int jt = jt0 + k;
            int jb = jt * 32;
            bool band = jt < 4 * ti + 4;

            const char* bufc = (const char*)smem + cur * BUF_BYTES;
            const float* hbuf = (const float*)(bufc + H_OFF);

            float hxj[2], hyj[2];
#pragma unroll
            for (int cg = 0; cg < 2; ++cg) {
                hxj[cg] = hbuf[cg * 16 + lrow];
                hyj[cg] = hbuf[32 + cg * 16 + lrow];
            }

            bf16x8 bfx[2][2], bfy[2][2];
#pragma unroll
            for (int cg = 0; cg < 2; ++cg)
#pragma unroll
                for (int kc = 0; kc < 2; ++kc) {
                    bfx[cg][kc] = *reinterpret_cast<const bf16x8*>(bufc + offb[cg][kc]);
                    bfy[cg][kc] = *reinterpret_cast<const bf16x8*>(bufc + 4096 + offb[cg][kc]);
                }

            // C init = -(h_i + h_j); MFMA output is the full base-2 exponent
            f32x4 gx[2][2], gy[2][2];
#pragma unroll
            for (int rg = 0; rg < 2; ++rg)
#pragma unroll
                for (int cg = 0; cg < 2; ++cg) {
                    gx[rg][cg] = nhxi4[rg] - hxj[cg];
                    gy[rg][cg] = nhyi4[rg] - hyj[cg];
                }

#pragma unroll
            for (int rg = 0; rg < 2; ++rg)
#pragma unroll
                for (int cg = 0; cg < 2; ++cg)
#pragma unroll
                    for (int kc = 0; kc < 2; ++kc) {
                        gx[rg][cg] = __builtin_amdgcn_mfma_f32_16x16x32_bf16(ax[rg][kc], bfx[cg][kc], gx[rg][cg], 0, 0, 0);
                        gy[rg][cg] = __builtin_amdgcn_mfma_f32_16x16x32_bf16(ay[rg][kc], bfy[cg][kc], gy[rg][cg], 0, 0, 0);
                    }

            // hierarchical max over all 32 exponents (left-nested -> v_max3 fusion),
            // then ONE wave-uniform branch for the whole epilogue.
            float m4[8];
#pragma unroll
            for (int rg = 0; rg < 2; ++rg)
#pragma unroll
                for (int cg = 0; cg < 2; ++cg) {
                    int idx = rg * 2 + cg;
                    m4[idx]     = fmaxf(fmaxf(fmaxf(gx[rg][cg][0], gx[rg][cg][1]), gx[rg][cg][2]), gx[rg][cg][3]);
                    m4[4 + idx] = fmaxf(fmaxf(fmaxf(gy[rg][cg][0], gy[rg][cg][1]), gy[rg][cg][2]), gy[rg][cg][3]);
                }
            float mA = fmaxf(fmaxf(m4[0], m4[1]), m4[2]);
            float mB = fmaxf(fmaxf(m4[3], m4[4]), m4[5]);
            float mC = fmaxf(m4[6], m4[7]);
            float mall = fmaxf(fmaxf(mA, mB), mC);

            if (__ballot(mall >= THR)) {
                float cax[2] = {0.f, 0.f}, cay[2] = {0.f, 0.f};
#pragma unroll
                for (int rg = 0; rg < 2; ++rg)
#pragma unroll
                    for (int cg = 0; cg < 2; ++cg)
#pragma unroll
                        for (int q = 0; q < 4; ++q) {
                            float kxv = __builtin_exp2f(gx[rg][cg][q]);
                            float kyv = __builtin_exp2f(gy[rg][cg][q]);
                            rpx[rg][q] += kxv;
                            rpy[rg][q] += kyv;
                            float prod = kxv * kyv;
                            if (band) {
                                t1_1 += prod;
                            } else {
                                t1_2 += prod;
                                cax[cg] += kxv;
                                cay[cg] += kyv;
                            }
                        }
                if (!band) {
#pragma unroll
                    for (int cg = 0; cg < 2; ++cg) {
                        float vx = cax[cg], vy = cay[cg];
                        vx += __shfl_xor(vx, 16); vx += __shfl_xor(vx, 32);
                        vy += __shfl_xor(vy, 16); vy += __shfl_xor(vy, 32);
                        if (khi == 0) {
                            atomicAdd(&a_raw[l * NN + jb + cg * 16 + lrow], vx);
                            atomicAdd(&b_raw[l * NN + jb + cg * 16 + lrow], vy);
                        }
                    }
                }
            }

            __syncthreads();
            cur ^= 1;
        }

        // flush row sums for this i-tile
#pragma unroll
        for (int rg = 0; rg < 2; ++rg)
#pragma unroll
            for (int q = 0; q < 4; ++q) {
                float vx = rpx[rg][q], vy = rpy[rg][q];
#pragma unroll
                for (int sh = 1; sh < 16; sh <<= 1) {
                    vx += __shfl_xor(vx, sh);
                    vy += __shfl_xor(vy, sh);
                }
                if (lrow == 0) {
                    int row = ibase + rg * 16 + khi * 4 + q;
                    atomicAdd(&a_raw[l * NN + row], vx);
                    atomicAdd(&b_raw[l * NN + row], vy);
                }
            }
    };

    // phase A: ti = p, units [u0, min(u1,c)), jt = 4p + u
    int a_lo = u0, a_hi = (u1 < c) ? u1 : c;
    if (a_lo < a_hi) run_phase(p, 4 * p + a_lo, a_hi - a_lo);

    // phase B: ti = 31-p, units [max(u0,c), u1), jt = 4(31-p) + (u - c)
    int b_lo = (u0 > c) ? u0 : c, b_hi = u1;
    if (b_lo < b_hi) run_phase(31 - p, 4 * (31 - p) + (b_lo - c), b_hi - b_lo);

    float v = t1_1 + 2.f * t1_2;
#pragma unroll
    for (int sh = 1; sh < 64; sh <<= 1) v += __shfl_xor(v, sh);
    if (lane == 0) atomicAdd(&t1[l], v);
}

// One block per l; S_l = T1 - (2/n) sum A_i B_i + (sum A)(sum B)/n^2; atomicAdd into out.
__global__ void finalize_kernel(const float* __restrict__ a_raw, const float* __restrict__ b_raw,
                                const float* __restrict__ t1, float* __restrict__ out) {
    int l = blockIdx.x;
    int t = threadIdx.x;
    int lane = t & 63, w = t >> 6;

    float sab = 0.f, sa = 0.f, sb = 0.f;
    for (int i = t; i < NN; i += 256) {
        float av = a_raw[l * NN + i], bv = b_raw[l * NN + i];
        sab = __builtin_fmaf(av, bv, sab);
        sa += av;
        sb += bv;
    }
#pragma unroll
    for (int s = 1; s < 64; s <<= 1) {
        sab += __shfl_xor(sab, s);
        sa  += __shfl_xor(sa, s);
        sb  += __shfl_xor(sb, s);
    }
    __shared__ float sh[3][4];
    if (lane == 0) { sh[0][w] = sab; sh[1][w] = sa; sh[2][w] = sb; }
    __syncthreads();
    if (t == 0) {
        float rab = sh[0][0] + sh[0][1] + sh[0][2] + sh[0][3];
        float ra  = sh[1][0] + sh[1][1] + sh[1][2] + sh[1][3];
        float rb  = sh[2][0] + sh[2][1] + sh[2][2] + sh[2][3];
        const float n = (float)NN;
        float S = t1[l] - (2.f / n) * rab + (ra * rb) / (n * n);
        atomicAdd(out, S / (4095.f * 4095.f));
    }
}

extern "C" void kernel_launch(void* const* d_in, const int* in_sizes, int n_in,
                              void* d_out, int out_size, void* d_ws, size_t ws_size,
                              hipStream_t stream) {
    const float* X = (const float*)d_in[0];
    const float* Y = (const float*)d_in[1];
    float* out = (float*)d_out;
    char* ws = (char*)d_ws;

    const size_t XB_OFF  = 0;                       // L*N*D bf16 = 8388608 B
    const size_t YB_OFF  = 8388608;
    const size_t HX_OFF  = 16777216;                // L*N fp32
    const size_t HY_OFF  = 17039360;
    const size_t A_OFF   = 17301504;                // L*N fp32
    const size_t B_OFF   = 17563648;
    const size_t T1_OFF  = 17825792;                // L fp32

    ushort* Xb  = (ushort*)(ws + XB_OFF);
    ushort* Yb  = (ushort*)(ws + YB_OFF);
    float* hx   = (float*)(ws + HX_OFF);
    float* hy   = (float*)(ws + HY_OFF);
    float* a_raw = (float*)(ws + A_OFF);
    float* b_raw = (float*)(ws + B_OFF);
    float* t1    = (float*)(ws + T1_OFF);

    hipMemsetAsync(ws + A_OFF, 0, 2 * 262144 + 64, stream);
    hipMemsetAsync(d_out, 0, sizeof(float), stream);

    prep_kernel<<<dim3(NN, 2), 256, 0, stream>>>(X, Y, Xb, Yb, hx, hy);
    hsic_tri<<<1024, 256, 0, stream>>>(Xb, Yb, hx, hy, a_raw, b_raw, t1);
    finalize_kernel<<<LL, 256, 0, stream>>>(a_raw, b_raw, t1, out);
}

// Round 5
// 87.537 us; speedup vs baseline: 4.9706x; 1.3013x over previous
//
#include <hip/hip_runtime.h>
#include <hip/hip_bf16.h>

typedef __attribute__((ext_vector_type(8))) short bf16x8;
typedef __attribute__((ext_vector_type(4))) float f32x4;

#define NN 4096
#define DD 64
#define LL 16
// sqrt(log2(e)): prescaling x by this makes dot = log2(e)*<x,x'>, so
// K = exp(dot - hi - hj) becomes exp2(dots - hsi - hsj) -> bare v_exp_f32.
#define SCALE 1.2011224087864498f
// skip threshold (base-2 exponent): skipped terms <= 2^-24 each.
#define THR -24.0f

__device__ __forceinline__ ushort f2bf(float f) {
    unsigned int u = __float_as_uint(f);
    unsigned int r = u + 0x7FFFu + ((u >> 16) & 1u);
    return (ushort)(r >> 16);
}
__device__ __forceinline__ float bf2f(ushort u) {
    return __uint_as_float(((unsigned int)u) << 16);
}

__device__ __forceinline__ void gload_lds16(const void* g, void* l) {
    __builtin_amdgcn_global_load_lds((const __attribute__((address_space(1))) unsigned int*)g,
                                     (__attribute__((address_space(3))) unsigned int*)l, 16, 0, 0);
}
__device__ __forceinline__ void gload_lds4(const void* g, void* l) {
    __builtin_amdgcn_global_load_lds((const __attribute__((address_space(1))) unsigned int*)g,
                                     (__attribute__((address_space(3))) unsigned int*)l, 4, 0, 0);
}

// Transpose (N,D,L) fp32 -> (L,N,D) bf16 with per-row 16B-chunk XOR swizzle
// (chunk co of row n stored at co ^ (n&7)), values prescaled by SCALE, and
// h[l][n] = 0.5 * sum_d xs_bf16^2 (fp32, from the SAME bf16 values MFMA sees).
__global__ void prep_kernel(const float* __restrict__ X, const float* __restrict__ Y,
                            ushort* __restrict__ Xb, ushort* __restrict__ Yb,
                            float* __restrict__ hx, float* __restrict__ hy) {
    const float* in = blockIdx.y ? Y : X;
    ushort* outb    = blockIdx.y ? Yb : Xb;
    float* h        = blockIdx.y ? hy : hx;

    __shared__ float lds[64 * 17];
    __shared__ float psum[16][17];

    int n = blockIdx.x;
    int t = threadIdx.x;
    const float* row = in + (size_t)n * (DD * LL);

#pragma unroll
    for (int r = 0; r < 4; ++r) {
        int e = t + r * 256;        // e = d*16 + l
        lds[(e >> 4) * 17 + (e & 15)] = row[e];
    }
    __syncthreads();

    int l = t >> 4, c = t & 15;
    float p = 0.f;
    ushort4 w;
    {
        float v0 = lds[(c * 4 + 0) * 17 + l] * SCALE;
        float v1 = lds[(c * 4 + 1) * 17 + l] * SCALE;
        float v2 = lds[(c * 4 + 2) * 17 + l] * SCALE;
        float v3 = lds[(c * 4 + 3) * 17 + l] * SCALE;
        ushort u0 = f2bf(v0), u1 = f2bf(v1), u2 = f2bf(v2), u3 = f2bf(v3);
        float b0 = bf2f(u0), b1 = bf2f(u1), b2 = bf2f(u2), b3 = bf2f(u3);
        p = b0 * b0 + b1 * b1 + b2 * b2 + b3 * b3;
        w.x = u0; w.y = u1; w.z = u2; w.w = u3;
    }
    int cs = (c >> 1) ^ (n & 7);
    *reinterpret_cast<ushort4*>(outb + ((size_t)l * NN + n) * DD + cs * 8 + (c & 1) * 4) = w;

    psum[l][c] = p;
    __syncthreads();
    if (t < 16) {
        float s = 0.f;
#pragma unroll
        for (int i = 0; i < 16; ++i) s += psum[t][i];
        h[t * NN + n] = 0.5f * s;
    }
}

// LDS: 4 buffers x 8448 B (2-deep prefetch pipeline).
// Per buffer: [X 32x128B swizzled][Y 32x128B][h 256B = hx32,hy32].
#define BUF_BYTES 8448
#define H_OFF 8192
#define NBUF 4

// Uniform 3 VMEM ops per wave per stage (2x gload16 + 1x gload4 h-dup).
__device__ __forceinline__ void stage_tile(char* smem, int buf, int wave, int lane,
                                           const ushort* __restrict__ Xl, const ushort* __restrict__ Yl,
                                           const float* __restrict__ hxl, const float* __restrict__ hyl,
                                           int jb) {
    char* base = smem + buf * BUF_BYTES;
    const ushort* mat = (wave < 2) ? Xl : Yl;
#pragma unroll
    for (int q = 0; q < 2; ++q) {
        int ridx = wave * 2 + q;                  // 0..7 -> mat*4 + rowgroup
        int rbase = (ridx & 3) * 8;
        const ushort* src = mat + (size_t)(jb + rbase + (lane >> 3)) * DD + (lane & 7) * 8;
        gload_lds16(src, base + ridx * 1024);
    }
    // all waves duplicate-stage h (identical data, benign race, uniform vmcnt count)
    const float* hsrc = (lane < 32) ? (hxl + jb + lane) : (hyl + jb + (lane - 32));
    gload_lds4(hsrc, base + H_OFF);
}

// Triangular fused kernel, 256-row i-tiles. Grid = 16 l x 8 pairs x 4 segs = 512.
// Pair p owns i-tiles {p, 15-p}; per i-tile ti, j-units jt in [8ti, 128) (128-8ti
// units); pair total 136 = 4 segments x 34. Band units (jt-8ti < 8): diagonal
// 256x256 block computed fully, weight 1, row sums only. Strict-upper: weight 2
// for T1, col sums mirrored. Per wave: 64i x 32j via 32 MFMA.
__global__ __launch_bounds__(256, 2) void hsic_tri(
    const ushort* __restrict__ Xb, const ushort* __restrict__ Yb,
    const float* __restrict__ hx, const float* __restrict__ hy,
    float* __restrict__ a_raw, float* __restrict__ b_raw, float* __restrict__ t1) {

    int blk = blockIdx.x;                 // 512
    int l = (blk & 7) * 2 + ((blk >> 3) & 1);   // XCD-pinned l pair
    int rest = blk >> 4;                  // 0..31
    int p = rest >> 2;                    // 0..7
    int seg = rest & 3;                   // 0..3
    int c = 128 - 8 * p;                  // units in phase A (ti = p)
    int u0 = seg * 34, u1 = u0 + 34;

    int wave = threadIdx.x >> 6;
    int lane = threadIdx.x & 63;
    int lrow = lane & 15;
    int khi  = lane >> 4;

    const ushort* Xl = Xb + (size_t)l * (NN * DD);
    const ushort* Yl = Yb + (size_t)l * (NN * DD);
    const float* hxl = hx + l * NN;
    const float* hyl = hy + l * NN;

    __shared__ __align__(16) char smem[NBUF * BUF_BYTES];

    float t1_1 = 0.f, t1_2 = 0.f;

    // per-lane LDS byte offsets for B fragments (constant)
    int offb[2][2];
#pragma unroll
    for (int cg = 0; cg < 2; ++cg)
#pragma unroll
        for (int kc = 0; kc < 2; ++kc)
            offb[cg][kc] = (cg * 16 + lrow) * 128 + (((kc * 4 + khi) ^ (lrow & 7)) * 16);

    auto run_phase = [&](int ti, int jt0, int cnt) {
        __syncthreads();                  // protect buffers from previous phase
        int ibase = ti * 256 + wave * 64;

        bf16x8 ax[4][2], ay[4][2];
        f32x4 nhxi4[4], nhyi4[4];
#pragma unroll
        for (int rg = 0; rg < 4; ++rg) {
            int arow = ibase + rg * 16 + lrow;
#pragma unroll
            for (int kc = 0; kc < 2; ++kc) {
                int cs = (kc * 4 + khi) ^ (arow & 7);
                ax[rg][kc] = *reinterpret_cast<const bf16x8*>(Xl + (size_t)arow * DD + cs * 8);
                ay[rg][kc] = *reinterpret_cast<const bf16x8*>(Yl + (size_t)arow * DD + cs * 8);
            }
            int crow = ibase + rg * 16 + khi * 4;
            f32x4 hv = *reinterpret_cast<const f32x4*>(hxl + crow);
            nhxi4[rg] = -hv;
            f32x4 hw = *reinterpret_cast<const f32x4*>(hyl + crow);
            nhyi4[rg] = -hw;
        }

        float rpx[4][4] = {}, rpy[4][4] = {};

        stage_tile(smem, 0, wave, lane, Xl, Yl, hxl, hyl, jt0 * 32);
        if (cnt > 1) stage_tile(smem, 1, wave, lane, Xl, Yl, hxl, hyl, (jt0 + 1) * 32);

        for (int k = 0; k < cnt; ++k) {
            if (k + 2 < cnt)
                stage_tile(smem, (k + 2) & (NBUF - 1), wave, lane, Xl, Yl, hxl, hyl, (jt0 + k + 2) * 32);

            // wait own S_k retired (counted, never drain mid-loop), then sync
            if (k + 2 < cnt)      asm volatile("s_waitcnt vmcnt(6)" ::: "memory");
            else if (k + 1 < cnt) asm volatile("s_waitcnt vmcnt(3)" ::: "memory");
            else                  asm volatile("s_waitcnt vmcnt(0)" ::: "memory");
            __builtin_amdgcn_s_barrier();
            __builtin_amdgcn_sched_barrier(0);

            int jt = jt0 + k;
            int jb = jt * 32;
            bool band = (jt - 8 * ti) < 8;

            const char* bufc = smem + (k & (NBUF - 1)) * BUF_BYTES;
            const float* hbuf = (const float*)(bufc + H_OFF);

            float hxj[2], hyj[2];
#pragma unroll
            for (int cg = 0; cg < 2; ++cg) {
                hxj[cg] = hbuf[cg * 16 + lrow];
                hyj[cg] = hbuf[32 + cg * 16 + lrow];
            }

            bf16x8 bfx[2][2], bfy[2][2];
#pragma unroll
            for (int cg = 0; cg < 2; ++cg)
#pragma unroll
                for (int kc = 0; kc < 2; ++kc) {
                    bfx[cg][kc] = *reinterpret_cast<const bf16x8*>(bufc + offb[cg][kc]);
                    bfy[cg][kc] = *reinterpret_cast<const bf16x8*>(bufc + 4096 + offb[cg][kc]);
                }

            // C init = -(h_i + h_j); MFMA output is the full base-2 exponent
            f32x4 gx[4][2], gy[4][2];
#pragma unroll
            for (int rg = 0; rg < 4; ++rg)
#pragma unroll
                for (int cg = 0; cg < 2; ++cg) {
                    gx[rg][cg] = nhxi4[rg] - hxj[cg];
                    gy[rg][cg] = nhyi4[rg] - hyj[cg];
                }

#pragma unroll
            for (int rg = 0; rg < 4; ++rg)
#pragma unroll
                for (int cg = 0; cg < 2; ++cg)
#pragma unroll
                    for (int kc = 0; kc < 2; ++kc) {
                        gx[rg][cg] = __builtin_amdgcn_mfma_f32_16x16x32_bf16(ax[rg][kc], bfx[cg][kc], gx[rg][cg], 0, 0, 0);
                        gy[rg][cg] = __builtin_amdgcn_mfma_f32_16x16x32_bf16(ay[rg][kc], bfy[cg][kc], gy[rg][cg], 0, 0, 0);
                    }

            // max over all 64 exponents (left-nested triples -> v_max3), one branch
            float mt[16];
#pragma unroll
            for (int rg = 0; rg < 4; ++rg)
#pragma unroll
                for (int cg = 0; cg < 2; ++cg) {
                    int idx = rg * 2 + cg;
                    mt[idx]     = fmaxf(fmaxf(fmaxf(gx[rg][cg][0], gx[rg][cg][1]), gx[rg][cg][2]), gx[rg][cg][3]);
                    mt[8 + idx] = fmaxf(fmaxf(fmaxf(gy[rg][cg][0], gy[rg][cg][1]), gy[rg][cg][2]), gy[rg][cg][3]);
                }
            float m0 = fmaxf(fmaxf(fmaxf(mt[0], mt[1]), mt[2]), mt[3]);
            float m1 = fmaxf(fmaxf(fmaxf(mt[4], mt[5]), mt[6]), mt[7]);
            float m2 = fmaxf(fmaxf(fmaxf(mt[8], mt[9]), mt[10]), mt[11]);
            float m3 = fmaxf(fmaxf(fmaxf(mt[12], mt[13]), mt[14]), mt[15]);
            float mall = fmaxf(fmaxf(m0, m1), fmaxf(m2, m3));

            if (__ballot(mall >= THR)) {
                float cax[2] = {0.f, 0.f}, cay[2] = {0.f, 0.f};
#pragma unroll
                for (int rg = 0; rg < 4; ++rg)
#pragma unroll
                    for (int cg = 0; cg < 2; ++cg)
#pragma unroll
                        for (int q = 0; q < 4; ++q) {
                            float kxv = __builtin_exp2f(gx[rg][cg][q]);
                            float kyv = __builtin_exp2f(gy[rg][cg][q]);
                            rpx[rg][q] += kxv;
                            rpy[rg][q] += kyv;
                            float prod = kxv * kyv;
                            if (band) {
                                t1_1 += prod;
                            } else {
                                t1_2 += prod;
                                cax[cg] += kxv;
                                cay[cg] += kyv;
                            }
                        }
                if (!band) {
#pragma unroll
                    for (int cg = 0; cg < 2; ++cg) {
                        float vx = cax[cg], vy = cay[cg];
                        vx += __shfl_xor(vx, 16); vx += __shfl_xor(vx, 32);
                        vy += __shfl_xor(vy, 16); vy += __shfl_xor(vy, 32);
                        if (khi == 0) {
                            atomicAdd(&a_raw[l * NN + jb + cg * 16 + lrow], vx);
                            atomicAdd(&b_raw[l * NN + jb + cg * 16 + lrow], vy);
                        }
                    }
                }
            }
        }

        // flush row sums for this i-tile
#pragma unroll
        for (int rg = 0; rg < 4; ++rg)
#pragma unroll
            for (int q = 0; q < 4; ++q) {
                float vx = rpx[rg][q], vy = rpy[rg][q];
#pragma unroll
                for (int sh = 1; sh < 16; sh <<= 1) {
                    vx += __shfl_xor(vx, sh);
                    vy += __shfl_xor(vy, sh);
                }
                if (lrow == 0) {
                    int row = ibase + rg * 16 + khi * 4 + q;
                    atomicAdd(&a_raw[l * NN + row], vx);
                    atomicAdd(&b_raw[l * NN + row], vy);
                }
            }
    };

    // phase A: ti = p, units [u0, min(u1,c)), jt = 8p + u
    int a_lo = u0, a_hi = (u1 < c) ? u1 : c;
    if (a_lo < a_hi) run_phase(p, 8 * p + a_lo, a_hi - a_lo);

    // phase B: ti = 15-p, units [max(u0,c), u1), jt = 8(15-p) + (u - c)
    int b_lo = (u0 > c) ? u0 : c, b_hi = u1;
    if (b_lo < b_hi) run_phase(15 - p, 8 * (15 - p) + (b_lo - c), b_hi - b_lo);

    float v = t1_1 + 2.f * t1_2;
#pragma unroll
    for (int sh = 1; sh < 64; sh <<= 1) v += __shfl_xor(v, sh);
    if (lane == 0) atomicAdd(&t1[l], v);
}

// One block per l; S_l = T1 - (2/n) sum A_i B_i + (sum A)(sum B)/n^2; atomicAdd into out.
__global__ void finalize_kernel(const float* __restrict__ a_raw, const float* __restrict__ b_raw,
                                const float* __restrict__ t1, float* __restrict__ out) {
    int l = blockIdx.x;
    int t = threadIdx.x;
    int lane = t & 63, w = t >> 6;

    float sab = 0.f, sa = 0.f, sb = 0.f;
    for (int i = t; i < NN; i += 256) {
        float av = a_raw[l * NN + i], bv = b_raw[l * NN + i];
        sab = __builtin_fmaf(av, bv, sab);
        sa += av;
        sb += bv;
    }
#pragma unroll
    for (int s = 1; s < 64; s <<= 1) {
        sab += __shfl_xor(sab, s);
        sa  += __shfl_xor(sa, s);
        sb  += __shfl_xor(sb, s);
    }
    __shared__ float sh[3][4];
    if (lane == 0) { sh[0][w] = sab; sh[1][w] = sa; sh[2][w] = sb; }
    __syncthreads();
    if (t == 0) {
        float rab = sh[0][0] + sh[0][1] + sh[0][2] + sh[0][3];
        float ra  = sh[1][0] + sh[1][1] + sh[1][2] + sh[1][3];
        float rb  = sh[2][0] + sh[2][1] + sh[2][2] + sh[2][3];
        const float n = (float)NN;
        float S = t1[l] - (2.f / n) * rab + (ra * rb) / (n * n);
        atomicAdd(out, S / (4095.f * 4095.f));
    }
}

extern "C" void kernel_launch(void* const* d_in, const int* in_sizes, int n_in,
                              void* d_out, int out_size, void* d_ws, size_t ws_size,
                              hipStream_t stream) {
    const float* X = (const float*)d_in[0];
    const float* Y = (const float*)d_in[1];
    float* out = (float*)d_out;
    char* ws = (char*)d_ws;

    const size_t XB_OFF  = 0;                       // L*N*D bf16 = 8388608 B
    const size_t YB_OFF  = 8388608;
    const size_t HX_OFF  = 16777216;                // L*N fp32
    const size_t HY_OFF  = 17039360;
    const size_t A_OFF   = 17301504;                // L*N fp32
    const size_t B_OFF   = 17563648;
    const size_t T1_OFF  = 17825792;                // L fp32

    ushort* Xb  = (ushort*)(ws + XB_OFF);
    ushort* Yb  = (ushort*)(ws + YB_OFF);
    float* hx   = (float*)(ws + HX_OFF);
    float* hy   = (float*)(ws + HY_OFF);
    float* a_raw = (float*)(ws + A_OFF);
    float* b_raw = (float*)(ws + B_OFF);
    float* t1    = (float*)(ws + T1_OFF);

    hipMemsetAsync(ws + A_OFF, 0, 2 * 262144 + 64, stream);
    hipMemsetAsync(d_out, 0, sizeof(float), stream);

    prep_kernel<<<dim3(NN, 2), 256, 0, stream>>>(X, Y, Xb, Yb, hx, hy);
    hsic_tri<<<512, 256, 0, stream>>>(Xb, Yb, hx, hy, a_raw, b_raw, t1);
    finalize_kernel<<<LL, 256, 0, stream>>>(a_raw, b_raw, t1, out);
}